// Round 10
// baseline (552.021 us; speedup 1.0000x reference)
//
#include <hip/hip_runtime.h>
#include <hip/hip_bf16.h>

#define BATCH 8192
#define NUM_LABELS 8190
#define CURW 2944   // padded cur width (K for level 5)
#define YW   8192   // ybuf row stride

typedef __attribute__((ext_vector_type(4))) float f32x4;
typedef __attribute__((ext_vector_type(8))) short bf16x8;

#define VMCNT(n) asm volatile("s_waitcnt vmcnt(" #n ")" ::: "memory")
#define BAR() do { asm volatile("" ::: "memory"); __builtin_amdgcn_s_barrier(); asm volatile("" ::: "memory"); } while (0)
#define WAITK(n) do { asm volatile("s_waitcnt lgkmcnt(" #n ")" ::: "memory"); __builtin_amdgcn_sched_barrier(0); } while (0)

// ---------- helpers ----------
__device__ __forceinline__ unsigned short f2bf(float f) {
  unsigned u = __builtin_bit_cast(unsigned, f);
  unsigned r = u + 0x7fffu + ((u >> 16) & 1u);   // RNE; inputs are finite
  return (unsigned short)(r >> 16);
}
__device__ __forceinline__ float bf2f(unsigned short b) {
  return __builtin_bit_cast(float, (unsigned)b << 16);
}
__device__ __forceinline__ void gload_lds16(const void* g, void* l) {
  __builtin_amdgcn_global_load_lds(
      (const __attribute__((address_space(1))) void*)g,
      (__attribute__((address_space(3))) void*)l,
      16, 0, 0);
}

// ---------- fused x-convert + pad-zeroing ----------
__global__ void k_prep_x(const float* __restrict__ x,
                         unsigned short* __restrict__ xraw,
                         unsigned short* __restrict__ cur) {
  const int TX = BATCH * 768 / 4;
  int i = blockIdx.x * 256 + threadIdx.x;
  if (i < TX) {
    float4 v = ((const float4*)x)[i];
    int e = i * 4;
    int row = e / 768;
    int col = e - row * 768;
    ushort4 a, c;
    a.x = f2bf(v.x); a.y = f2bf(v.y); a.z = f2bf(v.z); a.w = f2bf(v.w);
    c.x = f2bf(fmaxf(v.x, 0.f)); c.y = f2bf(fmaxf(v.y, 0.f));
    c.z = f2bf(fmaxf(v.z, 0.f)); c.w = f2bf(fmaxf(v.w, 0.f));
    *(ushort4*)(xraw + e) = a;
    *(ushort4*)(cur + (size_t)row * CURW + col) = c;
    return;
  }
  int j = i - TX;
  const int PP = 130;
  if (j < BATCH * PP) {
    int row = j / PP, p = j - row * PP;
    int col = p < 58 ? 774 + p : (p < 98 ? 856 + (p - 58) : 992 + (p - 98));
    cur[(size_t)row * CURW + col] = 0;
  }
}

// ---------- padded-col -> real-col map ----------
__device__ __forceinline__ int pad2real(int kp) {
  if (kp < 774)  return kp;
  if (kp < 832)  return -1;
  if (kp < 856)  return 774 + (kp - 832);
  if (kp < 896)  return -1;
  if (kp < 992)  return 798 + (kp - 896);
  if (kp < 1024) return -1;
  if (kp < 1408) return 894 + (kp - 1024);
  return 1278 + (kp - 1408);
}

template<int KPAD, int KREAL, int NREAL>
__device__ __forceinline__ void convW(int rel, const float* __restrict__ W,
                                      unsigned short* __restrict__ Wp) {
  int n = rel / KPAD, kp = rel - n * KPAD;
  int kr = pad2real(kp);
  float v = 0.f;
  if (n < NREAL && kr >= 0) v = W[(size_t)n * KREAL + kr];
  Wp[rel] = f2bf(v);
}

// ---------- all weight conversions + inverse permutation in one launch ----------
__global__ void k_convert_w_all(const float* __restrict__ W0, const float* __restrict__ W1,
                                const float* __restrict__ W2, const float* __restrict__ W3,
                                const float* __restrict__ W4, const float* __restrict__ W5,
                                const int* __restrict__ labels, int* __restrict__ inv,
                                unsigned short* __restrict__ wp) {
  int i = blockIdx.x * 256 + threadIdx.x;
  if (i < NUM_LABELS) inv[labels[i]] = i;
  if (i >= 20963328) return;
  if (i < 319488) {
    if (i < 98304)       convW<768, 768, 6>  (i,          W0, wp);
    else if (i < 204800) convW<832, 774, 24> (i - 98304,  W1, wp + 98304);
    else                 convW<896, 798, 96> (i - 204800, W2, wp + 204800);
  } else {
    if (i < 712704)       convW<1024, 894, 384>  (i - 319488,  W3, wp + 319488);
    else if (i < 2875392) convW<1408, 1278, 1536>(i - 712704,  W4, wp + 712704);
    else                  convW<2944, 2814, 6144>(i - 2875392, W5, wp + 2875392);
  }
}

// ---------- fused levels 0-2 ----------
__global__ __launch_bounds__(256, 2) void k_fused_small(
    const unsigned short* __restrict__ xraw,
    const unsigned short* __restrict__ w0p,
    const unsigned short* __restrict__ w1p,
    const unsigned short* __restrict__ w2p,
    const float* __restrict__ b0, const float* __restrict__ b1,
    const float* __restrict__ b2,
    unsigned short* __restrict__ ybuf,
    unsigned short* __restrict__ cur) {
  __shared__ __align__(16) unsigned short As[32 * 1000];
  const int tid = threadIdx.x;
  const int l = tid & 63, w = tid >> 6;
  const int l15 = l & 15, q8 = (l >> 4) * 8;
  const int row0 = blockIdx.x * 32;
  const int mi = w >> 1;
  const int nj0 = w & 1;

  {
    const int r = tid >> 3, c8 = tid & 7;
    const unsigned short* src = xraw + (size_t)(row0 + r) * 768 + c8 * 96;
    unsigned short* dst = As + r * 1000 + c8 * 96;
#pragma unroll
    for (int i = 0; i < 12; ++i)
      *(bf16x8*)(dst + i * 8) = *(const bf16x8*)(src + i * 8);
    unsigned short* dz = As + r * 1000 + 768 + c8 * 28;
    ushort4 z = {0, 0, 0, 0};
#pragma unroll
    for (int i = 0; i < 7; ++i) *(ushort4*)(dz + i * 4) = z;
  }
  __syncthreads();

  auto level = [&](int K, int ntiles, int Nr, const unsigned short* W, int ldw,
                   const float* bias, int ycol, int ccol) {
    for (int n = nj0; n < ntiles; n += 2) {
      f32x4 acc = {0.f, 0.f, 0.f, 0.f};
      const unsigned short* wrow = W + (size_t)(n * 16 + l15) * ldw + q8;
      const unsigned short* arow = As + (mi * 16 + l15) * 1000 + q8;
#pragma unroll 2
      for (int k0 = 0; k0 < K; k0 += 32) {
        bf16x8 af = *(const bf16x8*)(arow + k0);
        bf16x8 bf = *(const bf16x8*)(wrow + k0);
        acc = __builtin_amdgcn_mfma_f32_16x16x32_bf16(af, bf, acc, 0, 0, 0);
      }
      int col = n * 16 + l15;
      if (col < Nr) {
        float bv = bias[col];
#pragma unroll
        for (int j = 0; j < 4; ++j) {
          int rl = mi * 16 + (l >> 4) * 4 + j;
          float y = acc[j] + bv;
          ybuf[(size_t)(row0 + rl) * YW + ycol + col] = f2bf(y);
          As[rl * 1000 + ccol + col] = f2bf(fmaxf(y, 0.f));
        }
      }
    }
    __syncthreads();
  };

  level(768, 1, 6,  w0p, 768, b0, 0,  768);

  {
    const int r = tid >> 3, c8 = tid & 7;
    unsigned short* p = As + r * 1000 + c8 * 96;
#pragma unroll
    for (int i = 0; i < 12; ++i) {
      bf16x8 v = *(bf16x8*)(p + i * 8);
#pragma unroll
      for (int j = 0; j < 8; ++j)
        if (((unsigned short)v[j]) & 0x8000u) v[j] = 0;
      *(bf16x8*)(p + i * 8) = v;
    }
  }
  __syncthreads();

  level(832, 2, 24, w1p, 832, b1, 6,  832);
  level(896, 6, 96, w2p, 896, b2, 30, 896);

  {
    const int r = tid >> 3, c8 = tid & 7;
    const unsigned short* srcl = As + r * 1000 + 768 + c8 * 28;
    unsigned short* dstg = cur + (size_t)(row0 + r) * CURW + 768 + c8 * 28;
#pragma unroll
    for (int i = 0; i < 7; ++i)
      *(ushort4*)(dstg + i * 4) = *(const ushort4*)(srcl + i * 4);
  }
}

// ---------- level-3 GEMM: 128x128 tile, 4 waves ----------
__global__ __launch_bounds__(256, 2) void k_gemm(
    const unsigned short* __restrict__ A, int lda,
    const unsigned short* __restrict__ B, int ldb,
    const float* __restrict__ bias,
    unsigned short* __restrict__ ybuf,
    unsigned short* __restrict__ curout,
    int K, int Nreal, int yoff, int curoff) {
  __shared__ unsigned short Asmem[128 * 64];
  __shared__ unsigned short Bsmem[128 * 64];
  const int tid = threadIdx.x;
  const int lane = tid & 63;
  const int wid = tid >> 6;
  const int wr = wid >> 1, wc = wid & 1;
  const int brow = blockIdx.x * 128;
  const int bcol = blockIdx.y * 128;

  f32x4 acc[4][4] = {};

  for (int k0 = 0; k0 < K; k0 += 64) {
#pragma unroll
    for (int p = 0; p < 4; ++p) {
      int ch = wid * 4 + p;
      int eo = ch * 512 + lane * 8;
      int r = eo >> 6;
      int col = eo & 63;
      gload_lds16(A + (size_t)(brow + r) * lda + k0 + col, Asmem + ch * 512);
      gload_lds16(B + (size_t)(bcol + r) * ldb + k0 + col, Bsmem + ch * 512);
    }
    __syncthreads();
#pragma unroll
    for (int kk = 0; kk < 2; ++kk) {
      bf16x8 af[4], bfr[4];
      int colk = kk * 32 + (lane >> 4) * 8;
#pragma unroll
      for (int m = 0; m < 4; ++m)
        af[m] = *(const bf16x8*)(Asmem + (wr * 64 + m * 16 + (lane & 15)) * 64 + colk);
#pragma unroll
      for (int n = 0; n < 4; ++n)
        bfr[n] = *(const bf16x8*)(Bsmem + (wc * 64 + n * 16 + (lane & 15)) * 64 + colk);
#pragma unroll
      for (int m = 0; m < 4; ++m)
#pragma unroll
        for (int n = 0; n < 4; ++n)
          acc[m][n] = __builtin_amdgcn_mfma_f32_16x16x32_bf16(af[m], bfr[n], acc[m][n], 0, 0, 0);
    }
    __syncthreads();
  }

#pragma unroll
  for (int n = 0; n < 4; ++n) {
    int col = bcol + wc * 64 + n * 16 + (lane & 15);
    if (col >= Nreal) continue;
    float bv = bias[col];
#pragma unroll
    for (int m = 0; m < 4; ++m) {
#pragma unroll
      for (int j = 0; j < 4; ++j) {
        int row = brow + wr * 64 + m * 16 + (lane >> 4) * 4 + j;
        float y = acc[m][n][j] + bv;
        ybuf[(size_t)row * YW + yoff + col] = f2bf(y);
        if (curout) curout[(size_t)row * CURW + curoff + col] = f2bf(fmaxf(y, 0.f));
      }
    }
  }
}

// ---------- level-4 GEMM: 256x256 BK=64, 8 waves, R7 schedule (measured best 1WG/CU) ----------
__global__ __launch_bounds__(512, 2) void k_gemm256(
    const unsigned short* __restrict__ A, int lda,
    const unsigned short* __restrict__ B, int ldb,
    const float* __restrict__ bias,
    unsigned short* __restrict__ ybuf,
    unsigned short* __restrict__ curout,
    int K, int yoff, int curoff) {
  __shared__ __align__(16) unsigned short lds[65536];  // 128 KiB
  const int tid = threadIdx.x;
  const int l = tid & 63;
  const int w = tid >> 6;
  const int wr = w >> 2;
  const int wc = w & 3;
  const int l15 = l & 15;
  const int q8 = (l >> 4) * 8;
  const int sx = (l & 7) << 3;
  const int swz = ((l & 7) ^ (l >> 3)) * 8;

  const int bid = blockIdx.x;
  const int im = (bid & 7) * 4 + ((bid >> 3) & 3);
  const int in = bid >> 5;
  const int brow = im * 256, bcol = in * 256;

  const unsigned short* gAr0 = A + (size_t)(brow + w * 8 + (l >> 3)) * lda + swz;
  const unsigned short* gAr1 = gAr0 + (size_t)64 * lda;
  const unsigned short* gAr2 = gAr0 + (size_t)128 * lda;
  const unsigned short* gAr3 = gAr0 + (size_t)192 * lda;
  const unsigned short* gBr0 = B + (size_t)(bcol + w * 8 + (l >> 3)) * ldb + swz;
  const unsigned short* gBr1 = gBr0 + (size_t)64 * ldb;
  const unsigned short* gBr2 = gBr0 + (size_t)128 * ldb;
  const unsigned short* gBr3 = gBr0 + (size_t)192 * ldb;

  unsigned short* const dA00 = lds + w * 512;
  unsigned short* const dA01 = lds + 8192 + w * 512;
  unsigned short* const dA10 = lds + 16384 + w * 512;
  unsigned short* const dA11 = lds + 24576 + w * 512;
  unsigned short* const dB00 = lds + 32768 + w * 512;
  unsigned short* const dB01 = lds + 40960 + w * 512;
  unsigned short* const dB10 = lds + 49152 + w * 512;
  unsigned short* const dB11 = lds + 57344 + w * 512;

  const int cOff0 = (q8) ^ sx;
  const int cOff1 = (32 + q8) ^ sx;
  const int brB = (wc & 1) * 64;
  const unsigned short* const aB00 = lds + wr * 8192 + l15 * 64 + cOff0;
  const unsigned short* const aB01 = lds + wr * 8192 + l15 * 64 + cOff1;
  const unsigned short* const aB10 = lds + 16384 + wr * 8192 + l15 * 64 + cOff0;
  const unsigned short* const aB11 = lds + 16384 + wr * 8192 + l15 * 64 + cOff1;
  const unsigned short* const bB00 = lds + 32768 + (wc >> 1) * 8192 + (brB + l15) * 64 + cOff0;
  const unsigned short* const bB01 = lds + 32768 + (wc >> 1) * 8192 + (brB + l15) * 64 + cOff1;
  const unsigned short* const bB10 = lds + 49152 + (wc >> 1) * 8192 + (brB + l15) * 64 + cOff0;
  const unsigned short* const bB11 = lds + 49152 + (wc >> 1) * 8192 + (brB + l15) * 64 + cOff1;

  f32x4 acc[8][4] = {};
  bf16x8 aF[2][4], bF[2][4];

  auto stage2 = [&](const unsigned short* glo, const unsigned short* ghi,
                    unsigned short* dst, int koff) {
    gload_lds16(glo + koff, dst);
    gload_lds16(ghi + koff, dst + 4096);
  };
  auto ldAh = [&](const unsigned short* lo, const unsigned short* hi, int half) {
#pragma unroll
    for (int m = 0; m < 4; ++m) {
      aF[0][m] = *(const bf16x8*)(lo + (half * 64 + m * 16) * 64);
      aF[1][m] = *(const bf16x8*)(hi + (half * 64 + m * 16) * 64);
    }
  };
  auto ldB01f = [&](const unsigned short* lo, const unsigned short* hi) {
#pragma unroll
    for (int n = 0; n < 2; ++n) {
      bF[0][n] = *(const bf16x8*)(lo + n * 16 * 64);
      bF[1][n] = *(const bf16x8*)(hi + n * 16 * 64);
    }
  };
  auto ldB23f = [&](const unsigned short* lo, const unsigned short* hi) {
#pragma unroll
    for (int n = 2; n < 4; ++n) {
      bF[0][n] = *(const bf16x8*)(lo + n * 16 * 64);
      bF[1][n] = *(const bf16x8*)(hi + n * 16 * 64);
    }
  };
  auto MM4 = [&](int m, int mbase, int nbase) {
#pragma unroll
    for (int kk = 0; kk < 2; ++kk)
#pragma unroll
      for (int n = 0; n < 2; ++n)
        acc[mbase + m][nbase + n] = __builtin_amdgcn_mfma_f32_16x16x32_bf16(
            aF[kk][m], bF[kk][nbase + n], acc[mbase + m][nbase + n], 0, 0, 0);
  };
  auto MMAblk = [&](int mbase, int nbase) {
    __builtin_amdgcn_s_setprio(1);
#pragma unroll
    for (int kk = 0; kk < 2; ++kk)
#pragma unroll
      for (int m = 0; m < 4; ++m)
#pragma unroll
        for (int n = 0; n < 2; ++n)
          acc[mbase + m][nbase + n] = __builtin_amdgcn_mfma_f32_16x16x32_bf16(
              aF[kk][m], bF[kk][nbase + n], acc[mbase + m][nbase + n], 0, 0, 0);
    __builtin_amdgcn_s_setprio(0);
  };

#define LADDER(mb, nb, w0, w1, w2, w3) do { \
    __builtin_amdgcn_s_setprio(1); \
    WAITK(w0); MM4(0, mb, nb); \
    WAITK(w1); MM4(1, mb, nb); \
    WAITK(w2); MM4(2, mb, nb); \
    WAITK(w3); MM4(3, mb, nb); \
    __builtin_amdgcn_s_setprio(0); \
  } while (0)

  const int KT = K >> 6;
  const int NT2 = KT >> 1;

  stage2(gBr0, gBr1, dB00, 0);
  stage2(gBr2, gBr3, dB01, 0);
  stage2(gAr0, gAr1, dA00, 0);
  stage2(gAr2, gAr3, dA01, 0);
  stage2(gBr0, gBr1, dB10, 64);
  stage2(gBr2, gBr3, dB11, 64);
  stage2(gAr0, gAr1, dA10, 64);
  VMCNT(6);
  BAR();
  ldB01f(bB00, bB01);

  for (int it = 0; it < NT2; ++it) {
    const bool more = (it + 1 < NT2);
    stage2(gAr2, gAr3, dA11, 64);
    ldAh(aB00, aB01, 0);
    ldB23f(bB00, bB01);
    LADDER(0, 0, 10, 8, 6, 4);
    BAR();
    MMAblk(0, 2);
    BAR();
    if (more) stage2(gBr0, gBr1, dB00, 128);
    ldAh(aB00, aB01, 1);
    LADDER(4, 0, 6, 4, 2, 0);
    BAR();
    if (more) { stage2(gBr2, gBr3, dB01, 128); stage2(gAr0, gAr1, dA00, 128); VMCNT(6); }
    else      { VMCNT(0); }
    BAR();
    ldB01f(bB10, bB11);
    MMAblk(4, 2);
    BAR();
    if (more) stage2(gAr2, gAr3, dA01, 128);
    ldAh(aB10, aB11, 0);
    ldB23f(bB10, bB11);
    LADDER(0, 0, 10, 8, 6, 4);
    BAR();
    MMAblk(0, 2);
    BAR();
    if (more) stage2(gBr0, gBr1, dB10, 192);
    ldAh(aB10, aB11, 1);
    LADDER(4, 0, 6, 4, 2, 0);
    BAR();
    if (more) { stage2(gBr2, gBr3, dB11, 192); stage2(gAr0, gAr1, dA10, 192); VMCNT(6); }
    BAR();
    if (more) ldB01f(bB00, bB01);
    MMAblk(4, 2);
    BAR();
    gAr0 += 128; gAr1 += 128; gAr2 += 128; gAr3 += 128;
    gBr0 += 128; gBr1 += 128; gBr2 += 128; gBr3 += 128;
  }
#undef LADDER

  const int j4 = (l >> 4) * 4;
  float bv[4];
#pragma unroll
  for (int n = 0; n < 4; ++n) bv[n] = bias[bcol + wc * 64 + n * 16 + l15];
#pragma unroll
  for (int m = 0; m < 8; ++m) {
    int rowb = brow + wr * 128 + m * 16 + j4;
#pragma unroll
    for (int j = 0; j < 4; ++j) {
      size_t rbase = (size_t)(rowb + j);
#pragma unroll
      for (int n = 0; n < 4; ++n) {
        int col = bcol + wc * 64 + n * 16 + l15;
        float y = acc[m][n][j] + bv[n];
        ybuf[rbase * YW + yoff + col] = f2bf(y);
        if (curout) curout[rbase * CURW + curoff + col] = f2bf(fmaxf(y, 0.f));
      }
    }
  }
}

// ---------- level-5 GEMM: 256x256 BK=32, 64 KiB LDS -> 2 WG/CU ----------
// Mechanism: co-resident WGs overlap LDS-read/stage stream with MFMA stream
// (m114 pipe co-scheduling); 1-deep prefetch latency hidden by the other WG.
// Swizzle (64B rows, 4x16B slots): phys = log ^ ((row>>1)&3).
//   stage src slot = (l&3)^((l>>3)&3); read slot = (l>>4)^((l>>1)&3).
// One barrier per K-tile; WAITK ladder (8,6,4,2,0); VMCNT(0) publish.
__global__ __launch_bounds__(512, 2) void k_gemm_bk32(
    const unsigned short* __restrict__ A, int lda,
    const unsigned short* __restrict__ B, int ldb,
    const float* __restrict__ bias,
    unsigned short* __restrict__ ybuf,
    unsigned short* __restrict__ curout,
    int K, int yoff, int curoff) {
  __shared__ __align__(16) unsigned short lds[32768];  // 64 KiB: A[2][256][32] | B[2][256][32]
  const int tid = threadIdx.x;
  const int l = tid & 63;
  const int w = tid >> 6;
  const int wr = w >> 2;     // M half (128 rows)
  const int wc = w & 3;      // N quarter (64 cols)
  const int l15 = l & 15;

  const int bid = blockIdx.x;
  const int im = (bid & 7) * 4 + ((bid >> 3) & 3);
  const int in = bid >> 5;
  const int brow = im * 256, bcol = in * 256;

  // stage source: lane l -> row w*16 + (l>>2), col slot (l&3)^((l>>3)&3)
  const int srow = w * 16 + (l >> 2);
  const int sslot = ((l & 3) ^ ((l >> 3) & 3)) * 8;
  const unsigned short* gA0 = A + (size_t)(brow + srow) * lda + sslot;
  const unsigned short* gA1 = gA0 + (size_t)128 * lda;
  const unsigned short* gB0 = B + (size_t)(bcol + srow) * ldb + sslot;
  const unsigned short* gB1 = gB0 + (size_t)128 * ldb;

  // LDS (elems): Ab0=0, Ab1=8192, Bb0=16384, Bb1=24576 (8192 elems = 16KB each)
  unsigned short* const sA0 = lds + w * 512;
  unsigned short* const sA1 = lds + 8192 + w * 512;
  unsigned short* const sB0 = lds + 16384 + w * 512;
  unsigned short* const sB1 = lds + 24576 + w * 512;

  // read bases: phys slot = (l>>4) ^ ((l>>1)&3)
  const int rslot = (((l >> 4) ^ ((l >> 1) & 3))) * 8;
  const unsigned short* const aR0 = lds + (wr * 128 + l15) * 32 + rslot;
  const unsigned short* const aR1 = lds + 8192 + (wr * 128 + l15) * 32 + rslot;
  const unsigned short* const bR0 = lds + 16384 + (wc * 64 + l15) * 32 + rslot;
  const unsigned short* const bR1 = lds + 24576 + (wc * 64 + l15) * 32 + rslot;

  f32x4 acc[8][4] = {};
  bf16x8 aF[8], bF[4];

  auto stage0 = [&](int kt) {
    const int ko = kt * 32;
    gload_lds16(gA0 + ko, sA0);
    gload_lds16(gA1 + ko, sA0 + 4096);
    gload_lds16(gB0 + ko, sB0);
    gload_lds16(gB1 + ko, sB0 + 4096);
  };
  auto stage1 = [&](int kt) {
    const int ko = kt * 32;
    gload_lds16(gA0 + ko, sA1);
    gload_lds16(gA1 + ko, sA1 + 4096);
    gload_lds16(gB0 + ko, sB1);
    gload_lds16(gB1 + ko, sB1 + 4096);
  };
  auto body = [&](const unsigned short* aR, const unsigned short* bR) {
    // issue order: bF0, bF1, aF0..7, bF2, bF3  (12 ds_reads)
    bF[0] = *(const bf16x8*)(bR);
    bF[1] = *(const bf16x8*)(bR + 512);
#pragma unroll
    for (int m = 0; m < 8; ++m)
      aF[m] = *(const bf16x8*)(aR + m * 512);
    bF[2] = *(const bf16x8*)(bR + 1024);
    bF[3] = *(const bf16x8*)(bR + 1536);
    __builtin_amdgcn_s_setprio(1);
    WAITK(8);   // bF01 + aF01
#pragma unroll
    for (int m = 0; m < 2; ++m) {
      acc[m][0] = __builtin_amdgcn_mfma_f32_16x16x32_bf16(aF[m], bF[0], acc[m][0], 0, 0, 0);
      acc[m][1] = __builtin_amdgcn_mfma_f32_16x16x32_bf16(aF[m], bF[1], acc[m][1], 0, 0, 0);
    }
    WAITK(6);   // + aF23
#pragma unroll
    for (int m = 2; m < 4; ++m) {
      acc[m][0] = __builtin_amdgcn_mfma_f32_16x16x32_bf16(aF[m], bF[0], acc[m][0], 0, 0, 0);
      acc[m][1] = __builtin_amdgcn_mfma_f32_16x16x32_bf16(aF[m], bF[1], acc[m][1], 0, 0, 0);
    }
    WAITK(4);   // + aF45
#pragma unroll
    for (int m = 4; m < 6; ++m) {
      acc[m][0] = __builtin_amdgcn_mfma_f32_16x16x32_bf16(aF[m], bF[0], acc[m][0], 0, 0, 0);
      acc[m][1] = __builtin_amdgcn_mfma_f32_16x16x32_bf16(aF[m], bF[1], acc[m][1], 0, 0, 0);
    }
    WAITK(2);   // + aF67
#pragma unroll
    for (int m = 6; m < 8; ++m) {
      acc[m][0] = __builtin_amdgcn_mfma_f32_16x16x32_bf16(aF[m], bF[0], acc[m][0], 0, 0, 0);
      acc[m][1] = __builtin_amdgcn_mfma_f32_16x16x32_bf16(aF[m], bF[1], acc[m][1], 0, 0, 0);
    }
    WAITK(0);   // + bF23
#pragma unroll
    for (int m = 0; m < 8; ++m) {
      acc[m][2] = __builtin_amdgcn_mfma_f32_16x16x32_bf16(aF[m], bF[2], acc[m][2], 0, 0, 0);
      acc[m][3] = __builtin_amdgcn_mfma_f32_16x16x32_bf16(aF[m], bF[3], acc[m][3], 0, 0, 0);
    }
    __builtin_amdgcn_s_setprio(0);
  };

  const int KT = K >> 5;     // 92 for level 5 (even)
  const int NT2 = KT >> 1;

  // prologue: tile 0 -> buf0
  stage0(0);
  VMCNT(0);
  BAR();

  for (int t = 0; t < NT2; ++t) {
    const bool more = (t + 1 < NT2);
    // tile 2t (buf0); stage tile 2t+1 -> buf1 (buf1 last read ended pre-barrier)
    stage1(2 * t + 1);
    body(aR0, bR0);
    VMCNT(0);
    BAR();
    // tile 2t+1 (buf1); stage tile 2t+2 -> buf0
    if (more) stage0(2 * t + 2);
    body(aR1, bR1);
    if (more) VMCNT(0);
    BAR();
  }

  // epilogue
  const int j4 = (l >> 4) * 4;
  float bv[4];
#pragma unroll
  for (int n = 0; n < 4; ++n) bv[n] = bias[bcol + wc * 64 + n * 16 + l15];
#pragma unroll
  for (int m = 0; m < 8; ++m) {
    int rowb = brow + wr * 128 + m * 16 + j4;
#pragma unroll
    for (int j = 0; j < 4; ++j) {
      size_t rbase = (size_t)(rowb + j);
#pragma unroll
      for (int n = 0; n < 4; ++n) {
        int col = bcol + wc * 64 + n * 16 + l15;
        float y = acc[m][n][j] + bv[n];
        ybuf[rbase * YW + yoff + col] = f2bf(y);
        if (curout) curout[rbase * CURW + curoff + col] = f2bf(fmaxf(y, 0.f));
      }
    }
  }
}

// ---------- final gather: one row per block; ybuf row is L1-resident ----------
__global__ __launch_bounds__(256) void k_gather(
    const unsigned short* __restrict__ ybuf,
    const int* __restrict__ inv,
    float* __restrict__ out) {
  const int row = blockIdx.x;
  const unsigned short* yr = ybuf + (size_t)row * YW;
  float* orow = out + (size_t)row * NUM_LABELS;
  const int t = threadIdx.x;
#pragma unroll
  for (int it = 0; it < 16; ++it) {
    int idx = it * 256 + t;               // float2 slot in [0, 4095)
    if (idx < NUM_LABELS / 2) {
      int c2 = idx * 2;
      int2 iv = *(const int2*)(inv + c2);
      float2 v;
      v.x = bf2f(yr[iv.x]);
      v.y = bf2f(yr[iv.y]);
      *(float2*)(orow + c2) = v;
    }
  }
}

// ---------- launch ----------
extern "C" void kernel_launch(void* const* d_in, const int* in_sizes, int n_in,
                              void* d_out, int out_size, void* d_ws, size_t ws_size,
                              hipStream_t stream) {
  const float* x = (const float*)d_in[0];
  const float* W[6];
  const float* bias[6];
  for (int i = 0; i < 6; ++i) {
    W[i] = (const float*)d_in[1 + 2 * i];
    bias[i] = (const float*)d_in[2 + 2 * i];
  }
  const int* labels = (const int*)d_in[13];
  float* out = (float*)d_out;

  char* ws = (char*)d_ws;
  unsigned short* xraw = (unsigned short*)(ws);
  unsigned short* cur  = (unsigned short*)(ws + 12582912);
  unsigned short* wp   = (unsigned short*)(ws + 60817408);
  unsigned short* ybuf = (unsigned short*)(ws + 102744064);
  int* inv             = (int*)(ws + 236961792);

  static const int Kpad[6]   = {768, 832, 896, 1024, 1408, 2944};
  static const int Nreal[6]  = {6, 24, 96, 384, 1536, 6144};
  static const int Npad[6]   = {128, 128, 128, 384, 1536, 6144};
  static const size_t woff[6] = {0, 98304, 204800, 319488, 712704, 2875392};
  static const int yoff[6]   = {0, 6, 30, 126, 510, 2046};
  static const int curoff[6] = {768, 832, 896, 1024, 1408, 0};

  {
    int tot = BATCH * 768 / 4 + BATCH * 130;
    k_prep_x<<<(tot + 255) / 256, 256, 0, stream>>>(x, xraw, cur);
  }
  k_convert_w_all<<<(20963328 + 255) / 256, 256, 0, stream>>>(
      W[0], W[1], W[2], W[3], W[4], W[5], labels, inv, wp);

  // levels 0-2 fused
  k_fused_small<<<BATCH / 32, 256, 0, stream>>>(
      xraw, wp + woff[0], wp + woff[1], wp + woff[2],
      bias[0], bias[1], bias[2], ybuf, cur);

  // level 3: 128^2 kernel
  {
    dim3 grid(BATCH / 128, Npad[3] / 128);
    k_gemm<<<grid, 256, 0, stream>>>(cur, CURW, wp + woff[3], Kpad[3], bias[3], ybuf,
                                     cur, Kpad[3], Nreal[3], yoff[3], curoff[3]);
  }
  // level 4: BK=64 R7 kernel (1 WG/CU; grid 192 -> no 2-WG benefit)
  {
    int nwg = (BATCH / 256) * (Npad[4] / 256);
    k_gemm256<<<nwg, 512, 0, stream>>>(cur, CURW, wp + woff[4], Kpad[4], bias[4], ybuf,
                                       cur, Kpad[4], yoff[4], curoff[4]);
  }
  // level 5: BK=32 kernel, 64 KiB LDS -> 2 WG/CU
  {
    int nwg = (BATCH / 256) * (Npad[5] / 256);
    k_gemm_bk32<<<nwg, 512, 0, stream>>>(cur, CURW, wp + woff[5], Kpad[5], bias[5], ybuf,
                                         (unsigned short*)nullptr,
                                         Kpad[5], yoff[5], curoff[5]);
  }

  k_gather<<<BATCH, 256, 0, stream>>>(ybuf, inv, out);
}

// Round 11
// 551.993 us; speedup vs baseline: 1.0001x; 1.0001x over previous
//
#include <hip/hip_runtime.h>
#include <hip/hip_bf16.h>

#define BATCH 8192
#define NUM_LABELS 8190
#define CURW 2944   // padded cur width (K for level 5)
#define YW   8192   // ybuf row stride

typedef __attribute__((ext_vector_type(4))) float f32x4;
typedef __attribute__((ext_vector_type(8))) short bf16x8;

#define VMCNT(n) asm volatile("s_waitcnt vmcnt(" #n ")" ::: "memory")
#define BAR() do { asm volatile("" ::: "memory"); __builtin_amdgcn_s_barrier(); asm volatile("" ::: "memory"); } while (0)
#define WAITK(n) do { asm volatile("s_waitcnt lgkmcnt(" #n ")" ::: "memory"); __builtin_amdgcn_sched_barrier(0); } while (0)

// ---------- helpers ----------
__device__ __forceinline__ unsigned short f2bf(float f) {
  unsigned u = __builtin_bit_cast(unsigned, f);
  unsigned r = u + 0x7fffu + ((u >> 16) & 1u);   // RNE; inputs are finite
  return (unsigned short)(r >> 16);
}
__device__ __forceinline__ float bf2f(unsigned short b) {
  return __builtin_bit_cast(float, (unsigned)b << 16);
}
__device__ __forceinline__ void gload_lds16(const void* g, void* l) {
  __builtin_amdgcn_global_load_lds(
      (const __attribute__((address_space(1))) void*)g,
      (__attribute__((address_space(3))) void*)l,
      16, 0, 0);
}

// ---------- fused x-convert + pad-zeroing ----------
__global__ void k_prep_x(const float* __restrict__ x,
                         unsigned short* __restrict__ xraw,
                         unsigned short* __restrict__ cur) {
  const int TX = BATCH * 768 / 4;
  int i = blockIdx.x * 256 + threadIdx.x;
  if (i < TX) {
    float4 v = ((const float4*)x)[i];
    int e = i * 4;
    int row = e / 768;
    int col = e - row * 768;
    ushort4 a, c;
    a.x = f2bf(v.x); a.y = f2bf(v.y); a.z = f2bf(v.z); a.w = f2bf(v.w);
    c.x = f2bf(fmaxf(v.x, 0.f)); c.y = f2bf(fmaxf(v.y, 0.f));
    c.z = f2bf(fmaxf(v.z, 0.f)); c.w = f2bf(fmaxf(v.w, 0.f));
    *(ushort4*)(xraw + e) = a;
    *(ushort4*)(cur + (size_t)row * CURW + col) = c;
    return;
  }
  int j = i - TX;
  const int PP = 130;
  if (j < BATCH * PP) {
    int row = j / PP, p = j - row * PP;
    int col = p < 58 ? 774 + p : (p < 98 ? 856 + (p - 58) : 992 + (p - 98));
    cur[(size_t)row * CURW + col] = 0;
  }
}

// ---------- padded-col -> real-col map ----------
__device__ __forceinline__ int pad2real(int kp) {
  if (kp < 774)  return kp;
  if (kp < 832)  return -1;
  if (kp < 856)  return 774 + (kp - 832);
  if (kp < 896)  return -1;
  if (kp < 992)  return 798 + (kp - 896);
  if (kp < 1024) return -1;
  if (kp < 1408) return 894 + (kp - 1024);
  return 1278 + (kp - 1408);
}

template<int KPAD, int KREAL, int NREAL>
__device__ __forceinline__ void convW(int rel, const float* __restrict__ W,
                                      unsigned short* __restrict__ Wp) {
  int n = rel / KPAD, kp = rel - n * KPAD;
  int kr = pad2real(kp);
  float v = 0.f;
  if (n < NREAL && kr >= 0) v = W[(size_t)n * KREAL + kr];
  Wp[rel] = f2bf(v);
}

// ---------- all weight conversions + inverse permutation in one launch ----------
__global__ void k_convert_w_all(const float* __restrict__ W0, const float* __restrict__ W1,
                                const float* __restrict__ W2, const float* __restrict__ W3,
                                const float* __restrict__ W4, const float* __restrict__ W5,
                                const int* __restrict__ labels, int* __restrict__ inv,
                                unsigned short* __restrict__ wp) {
  int i = blockIdx.x * 256 + threadIdx.x;
  if (i < NUM_LABELS) inv[labels[i]] = i;
  if (i >= 20963328) return;
  if (i < 319488) {
    if (i < 98304)       convW<768, 768, 6>  (i,          W0, wp);
    else if (i < 204800) convW<832, 774, 24> (i - 98304,  W1, wp + 98304);
    else                 convW<896, 798, 96> (i - 204800, W2, wp + 204800);
  } else {
    if (i < 712704)       convW<1024, 894, 384>  (i - 319488,  W3, wp + 319488);
    else if (i < 2875392) convW<1408, 1278, 1536>(i - 712704,  W4, wp + 712704);
    else                  convW<2944, 2814, 6144>(i - 2875392, W5, wp + 2875392);
  }
}

// ---------- fused levels 0-2 ----------
__global__ __launch_bounds__(256, 2) void k_fused_small(
    const unsigned short* __restrict__ xraw,
    const unsigned short* __restrict__ w0p,
    const unsigned short* __restrict__ w1p,
    const unsigned short* __restrict__ w2p,
    const float* __restrict__ b0, const float* __restrict__ b1,
    const float* __restrict__ b2,
    unsigned short* __restrict__ ybuf,
    unsigned short* __restrict__ cur) {
  __shared__ __align__(16) unsigned short As[32 * 1000];
  const int tid = threadIdx.x;
  const int l = tid & 63, w = tid >> 6;
  const int l15 = l & 15, q8 = (l >> 4) * 8;
  const int row0 = blockIdx.x * 32;
  const int mi = w >> 1;
  const int nj0 = w & 1;

  {
    const int r = tid >> 3, c8 = tid & 7;
    const unsigned short* src = xraw + (size_t)(row0 + r) * 768 + c8 * 96;
    unsigned short* dst = As + r * 1000 + c8 * 96;
#pragma unroll
    for (int i = 0; i < 12; ++i)
      *(bf16x8*)(dst + i * 8) = *(const bf16x8*)(src + i * 8);
    unsigned short* dz = As + r * 1000 + 768 + c8 * 28;
    ushort4 z = {0, 0, 0, 0};
#pragma unroll
    for (int i = 0; i < 7; ++i) *(ushort4*)(dz + i * 4) = z;
  }
  __syncthreads();

  auto level = [&](int K, int ntiles, int Nr, const unsigned short* W, int ldw,
                   const float* bias, int ycol, int ccol) {
    for (int n = nj0; n < ntiles; n += 2) {
      f32x4 acc = {0.f, 0.f, 0.f, 0.f};
      const unsigned short* wrow = W + (size_t)(n * 16 + l15) * ldw + q8;
      const unsigned short* arow = As + (mi * 16 + l15) * 1000 + q8;
#pragma unroll 2
      for (int k0 = 0; k0 < K; k0 += 32) {
        bf16x8 af = *(const bf16x8*)(arow + k0);
        bf16x8 bf = *(const bf16x8*)(wrow + k0);
        acc = __builtin_amdgcn_mfma_f32_16x16x32_bf16(af, bf, acc, 0, 0, 0);
      }
      int col = n * 16 + l15;
      if (col < Nr) {
        float bv = bias[col];
#pragma unroll
        for (int j = 0; j < 4; ++j) {
          int rl = mi * 16 + (l >> 4) * 4 + j;
          float y = acc[j] + bv;
          ybuf[(size_t)(row0 + rl) * YW + ycol + col] = f2bf(y);
          As[rl * 1000 + ccol + col] = f2bf(fmaxf(y, 0.f));
        }
      }
    }
    __syncthreads();
  };

  level(768, 1, 6,  w0p, 768, b0, 0,  768);

  {
    const int r = tid >> 3, c8 = tid & 7;
    unsigned short* p = As + r * 1000 + c8 * 96;
#pragma unroll
    for (int i = 0; i < 12; ++i) {
      bf16x8 v = *(bf16x8*)(p + i * 8);
#pragma unroll
      for (int j = 0; j < 8; ++j)
        if (((unsigned short)v[j]) & 0x8000u) v[j] = 0;
      *(bf16x8*)(p + i * 8) = v;
    }
  }
  __syncthreads();

  level(832, 2, 24, w1p, 832, b1, 6,  832);
  level(896, 6, 96, w2p, 896, b2, 30, 896);

  {
    const int r = tid >> 3, c8 = tid & 7;
    const unsigned short* srcl = As + r * 1000 + 768 + c8 * 28;
    unsigned short* dstg = cur + (size_t)(row0 + r) * CURW + 768 + c8 * 28;
#pragma unroll
    for (int i = 0; i < 7; ++i)
      *(ushort4*)(dstg + i * 4) = *(const ushort4*)(srcl + i * 4);
  }
}

// ---------- level-3 GEMM: 128x128 tile, 4 waves ----------
__global__ __launch_bounds__(256, 2) void k_gemm(
    const unsigned short* __restrict__ A, int lda,
    const unsigned short* __restrict__ B, int ldb,
    const float* __restrict__ bias,
    unsigned short* __restrict__ ybuf,
    unsigned short* __restrict__ curout,
    int K, int Nreal, int yoff, int curoff) {
  __shared__ unsigned short Asmem[128 * 64];
  __shared__ unsigned short Bsmem[128 * 64];
  const int tid = threadIdx.x;
  const int lane = tid & 63;
  const int wid = tid >> 6;
  const int wr = wid >> 1, wc = wid & 1;
  const int brow = blockIdx.x * 128;
  const int bcol = blockIdx.y * 128;

  f32x4 acc[4][4] = {};

  for (int k0 = 0; k0 < K; k0 += 64) {
#pragma unroll
    for (int p = 0; p < 4; ++p) {
      int ch = wid * 4 + p;
      int eo = ch * 512 + lane * 8;
      int r = eo >> 6;
      int col = eo & 63;
      gload_lds16(A + (size_t)(brow + r) * lda + k0 + col, Asmem + ch * 512);
      gload_lds16(B + (size_t)(bcol + r) * ldb + k0 + col, Bsmem + ch * 512);
    }
    __syncthreads();
#pragma unroll
    for (int kk = 0; kk < 2; ++kk) {
      bf16x8 af[4], bfr[4];
      int colk = kk * 32 + (lane >> 4) * 8;
#pragma unroll
      for (int m = 0; m < 4; ++m)
        af[m] = *(const bf16x8*)(Asmem + (wr * 64 + m * 16 + (lane & 15)) * 64 + colk);
#pragma unroll
      for (int n = 0; n < 4; ++n)
        bfr[n] = *(const bf16x8*)(Bsmem + (wc * 64 + n * 16 + (lane & 15)) * 64 + colk);
#pragma unroll
      for (int m = 0; m < 4; ++m)
#pragma unroll
        for (int n = 0; n < 4; ++n)
          acc[m][n] = __builtin_amdgcn_mfma_f32_16x16x32_bf16(af[m], bfr[n], acc[m][n], 0, 0, 0);
    }
    __syncthreads();
  }

#pragma unroll
  for (int n = 0; n < 4; ++n) {
    int col = bcol + wc * 64 + n * 16 + (lane & 15);
    if (col >= Nreal) continue;
    float bv = bias[col];
#pragma unroll
    for (int m = 0; m < 4; ++m) {
#pragma unroll
      for (int j = 0; j < 4; ++j) {
        int row = brow + wr * 64 + m * 16 + (lane >> 4) * 4 + j;
        float y = acc[m][n][j] + bv;
        ybuf[(size_t)row * YW + yoff + col] = f2bf(y);
        if (curout) curout[(size_t)row * CURW + curoff + col] = f2bf(fmaxf(y, 0.f));
      }
    }
  }
}

// ---------- levels 4-5 GEMM: 256x128 tile, 4 waves, BK=32, 48 KiB LDS ----------
// 2 WGs/CU co-resident (regs ~232/wave -> 2 waves/SIMD; two 4-wave WGs fit).
// Barrier-independent WGs overlap: one WG's LDS/stage stream runs under the
// other's MFMA cluster (m114). Body/swizzle verified in R10's bk32 kernel
// (passed, 0 bank conflicts): stage slot (l&3)^((l>>3)&3), read slot
// (l>>4)^((l>>1)&3) -> phys = log ^ ((row>>1)&3) both sides.
__global__ __launch_bounds__(256, 2) void k_gemm_w4(
    const unsigned short* __restrict__ A, int lda,
    const unsigned short* __restrict__ B, int ldb,
    const float* __restrict__ bias,
    unsigned short* __restrict__ ybuf,
    unsigned short* __restrict__ curout,
    int K, int yoff, int curoff) {
  __shared__ __align__(16) unsigned short lds[24576];  // 48 KiB: A[2][256][32] | B[2][128][32]
  const int tid = threadIdx.x;
  const int l = tid & 63;
  const int w = tid >> 6;        // 0..3
  const int wr = w >> 1;         // 128-row half
  const int wc = w & 1;          // 64-col half
  const int l15 = l & 15;

  const int bid = blockIdx.x;
  const int im = (bid & 7) * 4 + ((bid >> 3) & 3);
  const int in = bid >> 5;
  const int brow = im * 256, bcol = in * 128;

  // stage source: lane l -> row w*16 + (l>>2) of a 64-row chunk, slot (l&3)^((l>>3)&3)
  const int srow = w * 16 + (l >> 2);
  const int sslot = ((l & 3) ^ ((l >> 3) & 3)) * 8;
  const unsigned short* gA = A + (size_t)(brow + srow) * lda + sslot;
  const unsigned short* gB = B + (size_t)(bcol + srow) * ldb + sslot;

  // LDS elem offsets: Ab0=0, Ab1=8192, Bb0=16384, Bb1=20480
  unsigned short* const sA0 = lds + w * 512;
  unsigned short* const sA1 = lds + 8192 + w * 512;
  unsigned short* const sB0 = lds + 16384 + w * 512;
  unsigned short* const sB1 = lds + 20480 + w * 512;

  const int rslot = ((l >> 4) ^ ((l >> 1) & 3)) * 8;
  const unsigned short* const aR0 = lds + (wr * 128 + l15) * 32 + rslot;
  const unsigned short* const aR1 = lds + 8192 + (wr * 128 + l15) * 32 + rslot;
  const unsigned short* const bR0 = lds + 16384 + (wc * 64 + l15) * 32 + rslot;
  const unsigned short* const bR1 = lds + 20480 + (wc * 64 + l15) * 32 + rslot;

  f32x4 acc[8][4] = {};
  bf16x8 aF[8], bF[4];

  auto stage0 = [&](int kt) {
    const int ko = kt * 32;
    gload_lds16(gA + ko, sA0);
    gload_lds16(gA + (size_t)64 * lda + ko, sA0 + 2048);
    gload_lds16(gA + (size_t)128 * lda + ko, sA0 + 4096);
    gload_lds16(gA + (size_t)192 * lda + ko, sA0 + 6144);
    gload_lds16(gB + ko, sB0);
    gload_lds16(gB + (size_t)64 * ldb + ko, sB0 + 2048);
  };
  auto stage1 = [&](int kt) {
    const int ko = kt * 32;
    gload_lds16(gA + ko, sA1);
    gload_lds16(gA + (size_t)64 * lda + ko, sA1 + 2048);
    gload_lds16(gA + (size_t)128 * lda + ko, sA1 + 4096);
    gload_lds16(gA + (size_t)192 * lda + ko, sA1 + 6144);
    gload_lds16(gB + ko, sB1);
    gload_lds16(gB + (size_t)64 * ldb + ko, sB1 + 2048);
  };
  auto body = [&](const unsigned short* aR, const unsigned short* bR) {
    // issue: bF0,bF1, aF0..7, bF2,bF3  (12 ds_reads), counted-lgkm MFMA ladder
    bF[0] = *(const bf16x8*)(bR);
    bF[1] = *(const bf16x8*)(bR + 512);
#pragma unroll
    for (int m = 0; m < 8; ++m)
      aF[m] = *(const bf16x8*)(aR + m * 512);
    bF[2] = *(const bf16x8*)(bR + 1024);
    bF[3] = *(const bf16x8*)(bR + 1536);
    __builtin_amdgcn_s_setprio(1);
    WAITK(8);
#pragma unroll
    for (int m = 0; m < 2; ++m) {
      acc[m][0] = __builtin_amdgcn_mfma_f32_16x16x32_bf16(aF[m], bF[0], acc[m][0], 0, 0, 0);
      acc[m][1] = __builtin_amdgcn_mfma_f32_16x16x32_bf16(aF[m], bF[1], acc[m][1], 0, 0, 0);
    }
    WAITK(6);
#pragma unroll
    for (int m = 2; m < 4; ++m) {
      acc[m][0] = __builtin_amdgcn_mfma_f32_16x16x32_bf16(aF[m], bF[0], acc[m][0], 0, 0, 0);
      acc[m][1] = __builtin_amdgcn_mfma_f32_16x16x32_bf16(aF[m], bF[1], acc[m][1], 0, 0, 0);
    }
    WAITK(4);
#pragma unroll
    for (int m = 4; m < 6; ++m) {
      acc[m][0] = __builtin_amdgcn_mfma_f32_16x16x32_bf16(aF[m], bF[0], acc[m][0], 0, 0, 0);
      acc[m][1] = __builtin_amdgcn_mfma_f32_16x16x32_bf16(aF[m], bF[1], acc[m][1], 0, 0, 0);
    }
    WAITK(2);
#pragma unroll
    for (int m = 6; m < 8; ++m) {
      acc[m][0] = __builtin_amdgcn_mfma_f32_16x16x32_bf16(aF[m], bF[0], acc[m][0], 0, 0, 0);
      acc[m][1] = __builtin_amdgcn_mfma_f32_16x16x32_bf16(aF[m], bF[1], acc[m][1], 0, 0, 0);
    }
    WAITK(0);
#pragma unroll
    for (int m = 0; m < 8; ++m) {
      acc[m][2] = __builtin_amdgcn_mfma_f32_16x16x32_bf16(aF[m], bF[2], acc[m][2], 0, 0, 0);
      acc[m][3] = __builtin_amdgcn_mfma_f32_16x16x32_bf16(aF[m], bF[3], acc[m][3], 0, 0, 0);
    }
    __builtin_amdgcn_s_setprio(0);
  };

  const int KT = K >> 5;     // 44 (L4) / 92 (L5) - even
  const int NT2 = KT >> 1;

  stage0(0);
  VMCNT(0);
  BAR();

  for (int t = 0; t < NT2; ++t) {
    const bool more = (t + 1 < NT2);
    stage1(2 * t + 1);          // buf1 free: last read ended before previous BAR
    body(aR0, bR0);
    VMCNT(0);
    BAR();
    if (more) stage0(2 * t + 2);
    body(aR1, bR1);
    if (more) VMCNT(0);
    BAR();
  }

  // epilogue
  const int j4 = (l >> 4) * 4;
  float bv[4];
#pragma unroll
  for (int n = 0; n < 4; ++n) bv[n] = bias[bcol + wc * 64 + n * 16 + l15];
#pragma unroll
  for (int m = 0; m < 8; ++m) {
    int rowb = brow + wr * 128 + m * 16 + j4;
#pragma unroll
    for (int j = 0; j < 4; ++j) {
      size_t rbase = (size_t)(rowb + j);
#pragma unroll
      for (int n = 0; n < 4; ++n) {
        int col = bcol + wc * 64 + n * 16 + l15;
        float y = acc[m][n][j] + bv[n];
        ybuf[rbase * YW + yoff + col] = f2bf(y);
        if (curout) curout[rbase * CURW + curoff + col] = f2bf(fmaxf(y, 0.f));
      }
    }
  }
}

// ---------- final gather: one row per block; ybuf row is L1-resident ----------
__global__ __launch_bounds__(256) void k_gather(
    const unsigned short* __restrict__ ybuf,
    const int* __restrict__ inv,
    float* __restrict__ out) {
  const int row = blockIdx.x;
  const unsigned short* yr = ybuf + (size_t)row * YW;
  float* orow = out + (size_t)row * NUM_LABELS;
  const int t = threadIdx.x;
#pragma unroll
  for (int it = 0; it < 16; ++it) {
    int idx = it * 256 + t;               // float2 slot in [0, 4095)
    if (idx < NUM_LABELS / 2) {
      int c2 = idx * 2;
      int2 iv = *(const int2*)(inv + c2);
      float2 v;
      v.x = bf2f(yr[iv.x]);
      v.y = bf2f(yr[iv.y]);
      *(float2*)(orow + c2) = v;
    }
  }
}

// ---------- launch ----------
extern "C" void kernel_launch(void* const* d_in, const int* in_sizes, int n_in,
                              void* d_out, int out_size, void* d_ws, size_t ws_size,
                              hipStream_t stream) {
  const float* x = (const float*)d_in[0];
  const float* W[6];
  const float* bias[6];
  for (int i = 0; i < 6; ++i) {
    W[i] = (const float*)d_in[1 + 2 * i];
    bias[i] = (const float*)d_in[2 + 2 * i];
  }
  const int* labels = (const int*)d_in[13];
  float* out = (float*)d_out;

  char* ws = (char*)d_ws;
  unsigned short* xraw = (unsigned short*)(ws);
  unsigned short* cur  = (unsigned short*)(ws + 12582912);
  unsigned short* wp   = (unsigned short*)(ws + 60817408);
  unsigned short* ybuf = (unsigned short*)(ws + 102744064);
  int* inv             = (int*)(ws + 236961792);

  static const int Kpad[6]   = {768, 832, 896, 1024, 1408, 2944};
  static const int Nreal[6]  = {6, 24, 96, 384, 1536, 6144};
  static const int Npad[6]   = {128, 128, 128, 384, 1536, 6144};
  static const size_t woff[6] = {0, 98304, 204800, 319488, 712704, 2875392};
  static const int yoff[6]   = {0, 6, 30, 126, 510, 2046};
  static const int curoff[6] = {768, 832, 896, 1024, 1408, 0};

  {
    int tot = BATCH * 768 / 4 + BATCH * 130;
    k_prep_x<<<(tot + 255) / 256, 256, 0, stream>>>(x, xraw, cur);
  }
  k_convert_w_all<<<(20963328 + 255) / 256, 256, 0, stream>>>(
      W[0], W[1], W[2], W[3], W[4], W[5], labels, inv, wp);

  // levels 0-2 fused
  k_fused_small<<<BATCH / 32, 256, 0, stream>>>(
      xraw, wp + woff[0], wp + woff[1], wp + woff[2],
      bias[0], bias[1], bias[2], ybuf, cur);

  // level 3: 128^2 kernel
  {
    dim3 grid(BATCH / 128, Npad[3] / 128);
    k_gemm<<<grid, 256, 0, stream>>>(cur, CURW, wp + woff[3], Kpad[3], bias[3], ybuf,
                                     cur, Kpad[3], Nreal[3], yoff[3], curoff[3]);
  }
  // level 4: 256x128-tile 4-wave kernel (384 WGs)
  {
    int nwg = (BATCH / 256) * (Npad[4] / 128);
    k_gemm_w4<<<nwg, 256, 0, stream>>>(cur, CURW, wp + woff[4], Kpad[4], bias[4], ybuf,
                                       cur, Kpad[4], yoff[4], curoff[4]);
  }
  // level 5: 256x128-tile 4-wave kernel (1536 WGs, 2 WG/CU)
  {
    int nwg = (BATCH / 256) * (Npad[5] / 128);
    k_gemm_w4<<<nwg, 256, 0, stream>>>(cur, CURW, wp + woff[5], Kpad[5], bias[5], ybuf,
                                       (unsigned short*)nullptr,
                                       Kpad[5], yoff[5], curoff[5]);
  }

  k_gather<<<BATCH, 256, 0, stream>>>(ybuf, inv, out);
}

// Round 12
// 525.389 us; speedup vs baseline: 1.0507x; 1.0506x over previous
//
#include <hip/hip_runtime.h>
#include <hip/hip_bf16.h>

#define BATCH 8192
#define NUM_LABELS 8190
#define CURW 2944   // padded cur width (K for level 5)
#define YW   8192   // ybuf row stride

typedef __attribute__((ext_vector_type(4))) float f32x4;
typedef __attribute__((ext_vector_type(8))) short bf16x8;

#define VMCNT(n) asm volatile("s_waitcnt vmcnt(" #n ")" ::: "memory")
#define BAR() do { asm volatile("" ::: "memory"); __builtin_amdgcn_s_barrier(); asm volatile("" ::: "memory"); } while (0)
#define WAITK(n) do { asm volatile("s_waitcnt lgkmcnt(" #n ")" ::: "memory"); __builtin_amdgcn_sched_barrier(0); } while (0)

// ---------- helpers ----------
__device__ __forceinline__ unsigned short f2bf(float f) {
  unsigned u = __builtin_bit_cast(unsigned, f);
  unsigned r = u + 0x7fffu + ((u >> 16) & 1u);   // RNE; inputs are finite
  return (unsigned short)(r >> 16);
}
__device__ __forceinline__ float bf2f(unsigned short b) {
  return __builtin_bit_cast(float, (unsigned)b << 16);
}
__device__ __forceinline__ void gload_lds16(const void* g, void* l) {
  __builtin_amdgcn_global_load_lds(
      (const __attribute__((address_space(1))) void*)g,
      (__attribute__((address_space(3))) void*)l,
      16, 0, 0);
}

// ---------- padded-col -> real-col map ----------
__device__ __forceinline__ int pad2real(int kp) {
  if (kp < 774)  return kp;
  if (kp < 832)  return -1;
  if (kp < 856)  return 774 + (kp - 832);
  if (kp < 896)  return -1;
  if (kp < 992)  return 798 + (kp - 896);
  if (kp < 1024) return -1;
  if (kp < 1408) return 894 + (kp - 1024);
  return 1278 + (kp - 1408);
}

template<int KPAD, int KREAL, int NREAL>
__device__ __forceinline__ void convW(int rel, const float* __restrict__ W,
                                      unsigned short* __restrict__ Wp) {
  int n = rel / KPAD, kp = rel - n * KPAD;
  int kr = pad2real(kp);
  float v = 0.f;
  if (n < NREAL && kr >= 0) v = W[(size_t)n * KREAL + kr];
  Wp[rel] = f2bf(v);
}

// ---------- single prep launch: x-convert + pad-zero + all W conversions + inv ----------
__global__ void k_prep_all(const float* __restrict__ x,
                           unsigned short* __restrict__ xraw,
                           unsigned short* __restrict__ cur,
                           const float* __restrict__ W0, const float* __restrict__ W1,
                           const float* __restrict__ W2, const float* __restrict__ W3,
                           const float* __restrict__ W4, const float* __restrict__ W5,
                           const int* __restrict__ labels, int* __restrict__ inv,
                           unsigned short* __restrict__ wp) {
  int i = blockIdx.x * 256 + threadIdx.x;
  // task A: inverse permutation
  if (i < NUM_LABELS) inv[labels[i]] = i;
  // task B: x -> bf16 (raw + relu'd cur) then pad-zeroing  [disjoint sub-ranges]
  const int TX = BATCH * 768 / 4;           // 1,572,864
  if (i < TX) {
    float4 v = ((const float4*)x)[i];
    int e = i * 4;
    int row = e / 768;
    int col = e - row * 768;
    ushort4 a, c;
    a.x = f2bf(v.x); a.y = f2bf(v.y); a.z = f2bf(v.z); a.w = f2bf(v.w);
    c.x = f2bf(fmaxf(v.x, 0.f)); c.y = f2bf(fmaxf(v.y, 0.f));
    c.z = f2bf(fmaxf(v.z, 0.f)); c.w = f2bf(fmaxf(v.w, 0.f));
    *(ushort4*)(xraw + e) = a;
    *(ushort4*)(cur + (size_t)row * CURW + col) = c;
  } else if (i < TX + BATCH * 130) {
    int j = i - TX;
    const int PP = 130;
    int row = j / PP, p = j - row * PP;
    int col = p < 58 ? 774 + p : (p < 98 ? 856 + (p - 58) : 992 + (p - 98));
    cur[(size_t)row * CURW + col] = 0;
  }
  // task C: weight conversion (covers all i < 20,963,328)
  if (i >= 20963328) return;
  if (i < 319488) {
    if (i < 98304)       convW<768, 768, 6>  (i,          W0, wp);
    else if (i < 204800) convW<832, 774, 24> (i - 98304,  W1, wp + 98304);
    else                 convW<896, 798, 96> (i - 204800, W2, wp + 204800);
  } else {
    if (i < 712704)       convW<1024, 894, 384>  (i - 319488,  W3, wp + 319488);
    else if (i < 2875392) convW<1408, 1278, 1536>(i - 712704,  W4, wp + 712704);
    else                  convW<2944, 2814, 6144>(i - 2875392, W5, wp + 2875392);
  }
}

// ---------- fused levels 0-2 ----------
__global__ __launch_bounds__(256, 2) void k_fused_small(
    const unsigned short* __restrict__ xraw,
    const unsigned short* __restrict__ w0p,
    const unsigned short* __restrict__ w1p,
    const unsigned short* __restrict__ w2p,
    const float* __restrict__ b0, const float* __restrict__ b1,
    const float* __restrict__ b2,
    unsigned short* __restrict__ ybuf,
    unsigned short* __restrict__ cur) {
  __shared__ __align__(16) unsigned short As[32 * 1000];
  const int tid = threadIdx.x;
  const int l = tid & 63, w = tid >> 6;
  const int l15 = l & 15, q8 = (l >> 4) * 8;
  const int row0 = blockIdx.x * 32;
  const int mi = w >> 1;
  const int nj0 = w & 1;

  {
    const int r = tid >> 3, c8 = tid & 7;
    const unsigned short* src = xraw + (size_t)(row0 + r) * 768 + c8 * 96;
    unsigned short* dst = As + r * 1000 + c8 * 96;
#pragma unroll
    for (int i = 0; i < 12; ++i)
      *(bf16x8*)(dst + i * 8) = *(const bf16x8*)(src + i * 8);
    unsigned short* dz = As + r * 1000 + 768 + c8 * 28;
    ushort4 z = {0, 0, 0, 0};
#pragma unroll
    for (int i = 0; i < 7; ++i) *(ushort4*)(dz + i * 4) = z;
  }
  __syncthreads();

  auto level = [&](int K, int ntiles, int Nr, const unsigned short* W, int ldw,
                   const float* bias, int ycol, int ccol) {
    for (int n = nj0; n < ntiles; n += 2) {
      f32x4 acc = {0.f, 0.f, 0.f, 0.f};
      const unsigned short* wrow = W + (size_t)(n * 16 + l15) * ldw + q8;
      const unsigned short* arow = As + (mi * 16 + l15) * 1000 + q8;
#pragma unroll 2
      for (int k0 = 0; k0 < K; k0 += 32) {
        bf16x8 af = *(const bf16x8*)(arow + k0);
        bf16x8 bf = *(const bf16x8*)(wrow + k0);
        acc = __builtin_amdgcn_mfma_f32_16x16x32_bf16(af, bf, acc, 0, 0, 0);
      }
      int col = n * 16 + l15;
      if (col < Nr) {
        float bv = bias[col];
#pragma unroll
        for (int j = 0; j < 4; ++j) {
          int rl = mi * 16 + (l >> 4) * 4 + j;
          float y = acc[j] + bv;
          ybuf[(size_t)(row0 + rl) * YW + ycol + col] = f2bf(y);
          As[rl * 1000 + ccol + col] = f2bf(fmaxf(y, 0.f));
        }
      }
    }
    __syncthreads();
  };

  level(768, 1, 6,  w0p, 768, b0, 0,  768);

  {
    const int r = tid >> 3, c8 = tid & 7;
    unsigned short* p = As + r * 1000 + c8 * 96;
#pragma unroll
    for (int i = 0; i < 12; ++i) {
      bf16x8 v = *(bf16x8*)(p + i * 8);
#pragma unroll
      for (int j = 0; j < 8; ++j)
        if (((unsigned short)v[j]) & 0x8000u) v[j] = 0;
      *(bf16x8*)(p + i * 8) = v;
    }
  }
  __syncthreads();

  level(832, 2, 24, w1p, 832, b1, 6,  832);
  level(896, 6, 96, w2p, 896, b2, 30, 896);

  {
    const int r = tid >> 3, c8 = tid & 7;
    const unsigned short* srcl = As + r * 1000 + 768 + c8 * 28;
    unsigned short* dstg = cur + (size_t)(row0 + r) * CURW + 768 + c8 * 28;
#pragma unroll
    for (int i = 0; i < 7; ++i)
      *(ushort4*)(dstg + i * 4) = *(const ushort4*)(srcl + i * 4);
  }
}

// ---------- level-3 GEMM: 128x128 tile, 4 waves ----------
__global__ __launch_bounds__(256, 2) void k_gemm(
    const unsigned short* __restrict__ A, int lda,
    const unsigned short* __restrict__ B, int ldb,
    const float* __restrict__ bias,
    unsigned short* __restrict__ ybuf,
    unsigned short* __restrict__ curout,
    int K, int Nreal, int yoff, int curoff) {
  __shared__ unsigned short Asmem[128 * 64];
  __shared__ unsigned short Bsmem[128 * 64];
  const int tid = threadIdx.x;
  const int lane = tid & 63;
  const int wid = tid >> 6;
  const int wr = wid >> 1, wc = wid & 1;
  const int brow = blockIdx.x * 128;
  const int bcol = blockIdx.y * 128;

  f32x4 acc[4][4] = {};

  for (int k0 = 0; k0 < K; k0 += 64) {
#pragma unroll
    for (int p = 0; p < 4; ++p) {
      int ch = wid * 4 + p;
      int eo = ch * 512 + lane * 8;
      int r = eo >> 6;
      int col = eo & 63;
      gload_lds16(A + (size_t)(brow + r) * lda + k0 + col, Asmem + ch * 512);
      gload_lds16(B + (size_t)(bcol + r) * ldb + k0 + col, Bsmem + ch * 512);
    }
    __syncthreads();
#pragma unroll
    for (int kk = 0; kk < 2; ++kk) {
      bf16x8 af[4], bfr[4];
      int colk = kk * 32 + (lane >> 4) * 8;
#pragma unroll
      for (int m = 0; m < 4; ++m)
        af[m] = *(const bf16x8*)(Asmem + (wr * 64 + m * 16 + (lane & 15)) * 64 + colk);
#pragma unroll
      for (int n = 0; n < 4; ++n)
        bfr[n] = *(const bf16x8*)(Bsmem + (wc * 64 + n * 16 + (lane & 15)) * 64 + colk);
#pragma unroll
      for (int m = 0; m < 4; ++m)
#pragma unroll
        for (int n = 0; n < 4; ++n)
          acc[m][n] = __builtin_amdgcn_mfma_f32_16x16x32_bf16(af[m], bfr[n], acc[m][n], 0, 0, 0);
    }
    __syncthreads();
  }

#pragma unroll
  for (int n = 0; n < 4; ++n) {
    int col = bcol + wc * 64 + n * 16 + (lane & 15);
    if (col >= Nreal) continue;
    float bv = bias[col];
#pragma unroll
    for (int m = 0; m < 4; ++m) {
#pragma unroll
      for (int j = 0; j < 4; ++j) {
        int row = brow + wr * 64 + m * 16 + (lane >> 4) * 4 + j;
        float y = acc[m][n][j] + bv;
        ybuf[(size_t)row * YW + yoff + col] = f2bf(y);
        if (curout) curout[(size_t)row * CURW + curoff + col] = f2bf(fmaxf(y, 0.f));
      }
    }
  }
}

// ---------- big-level GEMM (levels 4-5): 256x256, 8 waves, R7 schedule ----------
// Measured-best across 6 structural variants (260us L5). Serial-pipe floor:
// 9147 cyc/iter = MFMA 4966 + LDS-read 4626 (verified R6-R11; cross-WG
// overlap refuted R11; larger wave-tile register-walled at 256 VGPR).
__global__ __launch_bounds__(512, 2) void k_gemm256(
    const unsigned short* __restrict__ A, int lda,
    const unsigned short* __restrict__ B, int ldb,
    const float* __restrict__ bias,
    unsigned short* __restrict__ ybuf,
    unsigned short* __restrict__ curout,
    int K, int yoff, int curoff) {
  __shared__ __align__(16) unsigned short lds[65536];  // 128 KiB
  const int tid = threadIdx.x;
  const int l = tid & 63;
  const int w = tid >> 6;
  const int wr = w >> 2;
  const int wc = w & 3;
  const int l15 = l & 15;
  const int q8 = (l >> 4) * 8;
  const int sx = (l & 7) << 3;
  const int swz = ((l & 7) ^ (l >> 3)) * 8;

  const int bid = blockIdx.x;
  const int im = (bid & 7) * 4 + ((bid >> 3) & 3);
  const int in = bid >> 5;
  const int brow = im * 256, bcol = in * 256;

  const unsigned short* gAr0 = A + (size_t)(brow + w * 8 + (l >> 3)) * lda + swz;
  const unsigned short* gAr1 = gAr0 + (size_t)64 * lda;
  const unsigned short* gAr2 = gAr0 + (size_t)128 * lda;
  const unsigned short* gAr3 = gAr0 + (size_t)192 * lda;
  const unsigned short* gBr0 = B + (size_t)(bcol + w * 8 + (l >> 3)) * ldb + swz;
  const unsigned short* gBr1 = gBr0 + (size_t)64 * ldb;
  const unsigned short* gBr2 = gBr0 + (size_t)128 * ldb;
  const unsigned short* gBr3 = gBr0 + (size_t)192 * ldb;

  unsigned short* const dA00 = lds + w * 512;
  unsigned short* const dA01 = lds + 8192 + w * 512;
  unsigned short* const dA10 = lds + 16384 + w * 512;
  unsigned short* const dA11 = lds + 24576 + w * 512;
  unsigned short* const dB00 = lds + 32768 + w * 512;
  unsigned short* const dB01 = lds + 40960 + w * 512;
  unsigned short* const dB10 = lds + 49152 + w * 512;
  unsigned short* const dB11 = lds + 57344 + w * 512;

  const int cOff0 = (q8) ^ sx;
  const int cOff1 = (32 + q8) ^ sx;
  const int brB = (wc & 1) * 64;
  const unsigned short* const aB00 = lds + wr * 8192 + l15 * 64 + cOff0;
  const unsigned short* const aB01 = lds + wr * 8192 + l15 * 64 + cOff1;
  const unsigned short* const aB10 = lds + 16384 + wr * 8192 + l15 * 64 + cOff0;
  const unsigned short* const aB11 = lds + 16384 + wr * 8192 + l15 * 64 + cOff1;
  const unsigned short* const bB00 = lds + 32768 + (wc >> 1) * 8192 + (brB + l15) * 64 + cOff0;
  const unsigned short* const bB01 = lds + 32768 + (wc >> 1) * 8192 + (brB + l15) * 64 + cOff1;
  const unsigned short* const bB10 = lds + 49152 + (wc >> 1) * 8192 + (brB + l15) * 64 + cOff0;
  const unsigned short* const bB11 = lds + 49152 + (wc >> 1) * 8192 + (brB + l15) * 64 + cOff1;

  f32x4 acc[8][4] = {};
  bf16x8 aF[2][4], bF[2][4];

  auto stage2 = [&](const unsigned short* glo, const unsigned short* ghi,
                    unsigned short* dst, int koff) {
    gload_lds16(glo + koff, dst);
    gload_lds16(ghi + koff, dst + 4096);
  };
  auto ldAh = [&](const unsigned short* lo, const unsigned short* hi, int half) {
#pragma unroll
    for (int m = 0; m < 4; ++m) {
      aF[0][m] = *(const bf16x8*)(lo + (half * 64 + m * 16) * 64);
      aF[1][m] = *(const bf16x8*)(hi + (half * 64 + m * 16) * 64);
    }
  };
  auto ldB01f = [&](const unsigned short* lo, const unsigned short* hi) {
#pragma unroll
    for (int n = 0; n < 2; ++n) {
      bF[0][n] = *(const bf16x8*)(lo + n * 16 * 64);
      bF[1][n] = *(const bf16x8*)(hi + n * 16 * 64);
    }
  };
  auto ldB23f = [&](const unsigned short* lo, const unsigned short* hi) {
#pragma unroll
    for (int n = 2; n < 4; ++n) {
      bF[0][n] = *(const bf16x8*)(lo + n * 16 * 64);
      bF[1][n] = *(const bf16x8*)(hi + n * 16 * 64);
    }
  };
  auto MM4 = [&](int m, int mbase, int nbase) {
#pragma unroll
    for (int kk = 0; kk < 2; ++kk)
#pragma unroll
      for (int n = 0; n < 2; ++n)
        acc[mbase + m][nbase + n] = __builtin_amdgcn_mfma_f32_16x16x32_bf16(
            aF[kk][m], bF[kk][nbase + n], acc[mbase + m][nbase + n], 0, 0, 0);
  };
  auto MMAblk = [&](int mbase, int nbase) {
    __builtin_amdgcn_s_setprio(1);
#pragma unroll
    for (int kk = 0; kk < 2; ++kk)
#pragma unroll
      for (int m = 0; m < 4; ++m)
#pragma unroll
        for (int n = 0; n < 2; ++n)
          acc[mbase + m][nbase + n] = __builtin_amdgcn_mfma_f32_16x16x32_bf16(
              aF[kk][m], bF[kk][nbase + n], acc[mbase + m][nbase + n], 0, 0, 0);
    __builtin_amdgcn_s_setprio(0);
  };

#define LADDER(mb, nb, w0, w1, w2, w3) do { \
    __builtin_amdgcn_s_setprio(1); \
    WAITK(w0); MM4(0, mb, nb); \
    WAITK(w1); MM4(1, mb, nb); \
    WAITK(w2); MM4(2, mb, nb); \
    WAITK(w3); MM4(3, mb, nb); \
    __builtin_amdgcn_s_setprio(0); \
  } while (0)

  const int KT = K >> 6;
  const int NT2 = KT >> 1;

  stage2(gBr0, gBr1, dB00, 0);
  stage2(gBr2, gBr3, dB01, 0);
  stage2(gAr0, gAr1, dA00, 0);
  stage2(gAr2, gAr3, dA01, 0);
  stage2(gBr0, gBr1, dB10, 64);
  stage2(gBr2, gBr3, dB11, 64);
  stage2(gAr0, gAr1, dA10, 64);
  VMCNT(6);
  BAR();
  ldB01f(bB00, bB01);

  for (int it = 0; it < NT2; ++it) {
    const bool more = (it + 1 < NT2);
    stage2(gAr2, gAr3, dA11, 64);
    ldAh(aB00, aB01, 0);
    ldB23f(bB00, bB01);
    LADDER(0, 0, 10, 8, 6, 4);
    BAR();
    MMAblk(0, 2);
    BAR();
    if (more) stage2(gBr0, gBr1, dB00, 128);
    ldAh(aB00, aB01, 1);
    LADDER(4, 0, 6, 4, 2, 0);
    BAR();
    if (more) { stage2(gBr2, gBr3, dB01, 128); stage2(gAr0, gAr1, dA00, 128); VMCNT(6); }
    else      { VMCNT(0); }
    BAR();
    ldB01f(bB10, bB11);
    MMAblk(4, 2);
    BAR();
    if (more) stage2(gAr2, gAr3, dA01, 128);
    ldAh(aB10, aB11, 0);
    ldB23f(bB10, bB11);
    LADDER(0, 0, 10, 8, 6, 4);
    BAR();
    MMAblk(0, 2);
    BAR();
    if (more) stage2(gBr0, gBr1, dB10, 192);
    ldAh(aB10, aB11, 1);
    LADDER(4, 0, 6, 4, 2, 0);
    BAR();
    if (more) { stage2(gBr2, gBr3, dB11, 192); stage2(gAr0, gAr1, dA10, 192); VMCNT(6); }
    BAR();
    if (more) ldB01f(bB00, bB01);
    MMAblk(4, 2);
    BAR();
    gAr0 += 128; gAr1 += 128; gAr2 += 128; gAr3 += 128;
    gBr0 += 128; gBr1 += 128; gBr2 += 128; gBr3 += 128;
  }
#undef LADDER

  const int j4 = (l >> 4) * 4;
  float bv[4];
#pragma unroll
  for (int n = 0; n < 4; ++n) bv[n] = bias[bcol + wc * 64 + n * 16 + l15];
#pragma unroll
  for (int m = 0; m < 8; ++m) {
    int rowb = brow + wr * 128 + m * 16 + j4;
#pragma unroll
    for (int j = 0; j < 4; ++j) {
      size_t rbase = (size_t)(rowb + j);
#pragma unroll
      for (int n = 0; n < 4; ++n) {
        int col = bcol + wc * 64 + n * 16 + l15;
        float y = acc[m][n][j] + bv[n];
        ybuf[rbase * YW + yoff + col] = f2bf(y);
        if (curout) curout[rbase * CURW + curoff + col] = f2bf(fmaxf(y, 0.f));
      }
    }
  }
}

// ---------- final gather: one row per block; ybuf row is L1-resident ----------
__global__ __launch_bounds__(256) void k_gather(
    const unsigned short* __restrict__ ybuf,
    const int* __restrict__ inv,
    float* __restrict__ out) {
  const int row = blockIdx.x;
  const unsigned short* yr = ybuf + (size_t)row * YW;
  float* orow = out + (size_t)row * NUM_LABELS;
  const int t = threadIdx.x;
#pragma unroll
  for (int it = 0; it < 16; ++it) {
    int idx = it * 256 + t;               // float2 slot in [0, 4095)
    if (idx < NUM_LABELS / 2) {
      int c2 = idx * 2;
      int2 iv = *(const int2*)(inv + c2);
      float2 v;
      v.x = bf2f(yr[iv.x]);
      v.y = bf2f(yr[iv.y]);
      *(float2*)(orow + c2) = v;
    }
  }
}

// ---------- launch ----------
extern "C" void kernel_launch(void* const* d_in, const int* in_sizes, int n_in,
                              void* d_out, int out_size, void* d_ws, size_t ws_size,
                              hipStream_t stream) {
  const float* x = (const float*)d_in[0];
  const float* W[6];
  const float* bias[6];
  for (int i = 0; i < 6; ++i) {
    W[i] = (const float*)d_in[1 + 2 * i];
    bias[i] = (const float*)d_in[2 + 2 * i];
  }
  const int* labels = (const int*)d_in[13];
  float* out = (float*)d_out;

  char* ws = (char*)d_ws;
  unsigned short* xraw = (unsigned short*)(ws);
  unsigned short* cur  = (unsigned short*)(ws + 12582912);
  unsigned short* wp   = (unsigned short*)(ws + 60817408);
  unsigned short* ybuf = (unsigned short*)(ws + 102744064);
  int* inv             = (int*)(ws + 236961792);

  static const int Kpad[6]   = {768, 832, 896, 1024, 1408, 2944};
  static const int Nreal[6]  = {6, 24, 96, 384, 1536, 6144};
  static const int Npad[6]   = {128, 128, 128, 384, 1536, 6144};
  static const size_t woff[6] = {0, 98304, 204800, 319488, 712704, 2875392};
  static const int yoff[6]   = {0, 6, 30, 126, 510, 2046};
  static const int curoff[6] = {768, 832, 896, 1024, 1408, 0};

  // single prep launch: x-convert + pads + all W conversions + inv
  k_prep_all<<<(20963328 + 255) / 256, 256, 0, stream>>>(
      x, xraw, cur, W[0], W[1], W[2], W[3], W[4], W[5], labels, inv, wp);

  // levels 0-2 fused
  k_fused_small<<<BATCH / 32, 256, 0, stream>>>(
      xraw, wp + woff[0], wp + woff[1], wp + woff[2],
      bias[0], bias[1], bias[2], ybuf, cur);

  // level 3: 128^2 kernel
  {
    dim3 grid(BATCH / 128, Npad[3] / 128);
    k_gemm<<<grid, 256, 0, stream>>>(cur, CURW, wp + woff[3], Kpad[3], bias[3], ybuf,
                                     cur, Kpad[3], Nreal[3], yoff[3], curoff[3]);
  }
  // levels 4-5: 256^2 R7 kernel, 2D-XCD decode
  for (int i = 4; i < 6; ++i) {
    int nwg = (BATCH / 256) * (Npad[i] / 256);
    k_gemm256<<<nwg, 512, 0, stream>>>(cur, CURW, wp + woff[i], Kpad[i], bias[i], ybuf,
                                       (i < 5) ? cur : (unsigned short*)nullptr,
                                       Kpad[i], yoff[i], curoff[i]);
  }

  k_gather<<<BATCH, 256, 0, stream>>>(ybuf, inv, out);
}